// Round 14
// baseline (124.667 us; speedup 1.0000x reference)
//
#include <hip/hip_runtime.h>

// SLAYER SNN forward, MI355X. Round 14.
// vs R13 (k1-focused; kf structurally unchanged):
//  - wl1 layout interleaved [(cin*8+e)*32 + cp*16 + f*2 + cl] and k1
//    accumulates channel-pairs in float2 -> enables v_pk_fma_f32 (2 FMA/instr,
//    the only path to the 157 TF fp32 rate). Tap order per output unchanged
//    (bit-exact; pk halves are IEEE fp32 FMA).
//  - k1 reads weights per-iteration from global (L1-hot) instead of LDS:
//    ~34 fewer LDS wave-instr; LDS pipe now ~matches packed VALU.
//  - u1 re-laid out as [n][t][neuron] (kf's 100 loads hit one 100 KB window).
//  - out-zeroing moved to k1's first 50 blocks; k0 is 1 block (fold only).
// kf: only the u1 base/stride change. All summation trees bit-identical.

#define DECAY 0.9048374180359595f   // exp(-1/10)

#define BAR_LGKM() asm volatile("s_waitcnt lgkmcnt(0)\n\ts_barrier" ::: "memory")
#define FENCE_LGKM() asm volatile("s_waitcnt lgkmcnt(0)" ::: "memory")

// ---------------- k0: fold weights (1 block) ----------------
// wl1[(cin*8+e)*32 + cp*16 + f*2 + cl], c = 2*cp+cl, e,f in 0..7  (512 floats)
// wl2[c2*68 + cin*16 + e*4 + f]                                   (544 floats)
__global__ __launch_bounds__(128) void k0_fold(const float* __restrict__ w1,
        const float* __restrict__ w2, const float* __restrict__ wp1,
        const float* __restrict__ wp2, float* __restrict__ wl1,
        float* __restrict__ wl2) {
    const int tid = threadIdx.x;
    const float p1 = wp1[0], p2 = wp2[0];
    for (int idx = tid; idx < 512; idx += 128) {
        const int cl = idx & 1, f = (idx >> 1) & 7, cp = (idx >> 4) & 1;
        const int e = (idx >> 5) & 7, cin = idx >> 8;
        const int cc = (2 * cp + cl) * 2 + cin;
        int alo = e - 3; if (alo < 0) alo = 0;
        int ahi = e;     if (ahi > 4) ahi = 4;
        int blo = f - 3; if (blo < 0) blo = 0;
        int bhi = f;     if (bhi > 4) bhi = 4;
        float s = 0.f;
        for (int a = alo; a <= ahi; ++a)
            for (int b = blo; b <= bhi; ++b)
                s += w1[cc * 25 + a * 5 + b];
        wl1[idx] = s * p1;   // idx == (cin*8+e)*32 + cp*16 + f*2 + cl
    }
    for (int idx = tid; idx < 512; idx += 128) {
        const int c2 = idx & 7, f = (idx >> 3) & 3, e = (idx >> 5) & 3, cin = idx >> 7;
        int alo = e - 1; if (alo < 0) alo = 0;
        int ahi = e;     if (ahi > 2) ahi = 2;
        int blo = f - 1; if (blo < 0) blo = 0;
        int bhi = f;     if (bhi > 2) bhi = 2;
        float s = 0.f;
        for (int aa = alo; aa <= ahi; ++aa)
            for (int bb = blo; bb <= bhi; ++bb)
                s += w2[((c2 * 4 + cin) * 3 + aa) * 3 + bb];
        wl2[c2 * 68 + cin * 16 + e * 4 + f] = s * p2;
    }
}

// ---------------- k1: conv1+pool1, 8x8-tap stride-4, packed-pair FMA ----------------
// 6400 one-wave blocks. Tile: [cin][36 prow x 36], perm(r)=(r&3)*9+(r>>2),
// logical col C at phys C+2. Lane = (cp, i, jh, eh); e = 4eh+et; partner lane^1
// butterfly gives full e-sum; lane writes channel 2cp+eh.
// Weights read from global per (cin,et) as 4 float4 = float2 wv2[8]
// (pair = channels 2cp, 2cp+1 for tap f) -> accp[jj] (float2) packs 2 FMAs.
__global__ __launch_bounds__(64) void k1(const float* __restrict__ x,
        const float* __restrict__ wg, float* __restrict__ u1,
        float* __restrict__ out) {
    __shared__ __align__(16) float xs[2 * 1296];   // 10.1 KB
    const int lane = threadIdx.x;
    const int frame = blockIdx.x;                  // = n*100 + t (x is n-major)
    const int n = frame / 100, t = frame % 100;

    // zero the atomic-target out (12800 floats) across the first 50 blocks
    if (blockIdx.x < 50)
        ((float4*)out)[blockIdx.x * 64 + lane] = make_float4(0.f, 0.f, 0.f, 0.f);

    // zero halo rows r{0,1,34,35} -> prows {0,9,26,35} (9 float4 each, 2 cin)
    #pragma unroll
    for (int m0 = 0; m0 < 128; m0 += 64) {
        const int m = m0 + lane;
        if (m < 72) {
            const int cin = m / 36, rem = m % 36;
            const int rr = rem / 9, q4 = rem % 9;
            const int pr = (rr == 0) ? 0 : (rr == 1) ? 9 : (rr == 2) ? 26 : 35;
            *(float4*)(xs + cin * 1296 + pr * 36 + q4 * 4) = make_float4(0.f, 0.f, 0.f, 0.f);
        }
    }
    // zero halo cols phys {0,1},{34,35} for all 36 prows, 2 cin
    #pragma unroll
    for (int m0 = 0; m0 < 192; m0 += 64) {
        const int m = m0 + lane;
        if (m < 144) {
            const int cin = m / 72, rem = m % 72;
            const int side = rem & 1, pr = rem >> 1;
            *(float2*)(xs + cin * 1296 + pr * 36 + side * 34) = make_float2(0.f, 0.f);
        }
    }
    // stage frame: 512 float4, 8 per lane, coalesced
    const float4* xg = (const float4*)(x + (size_t)frame * 2048);
    #pragma unroll
    for (int q = 0; q < 8; ++q) {
        const int m = q * 64 + lane;
        const float4 v = xg[m];
        const int li = 4 * m;
        const int cin = li >> 10, row = (li >> 5) & 31, col = li & 31;
        const int r = row + 2;
        const int pr = (r & 3) * 9 + (r >> 2);
        float* d = xs + cin * 1296 + pr * 36 + col + 2;
        *(float2*)(d)     = make_float2(v.x, v.y);
        *(float2*)(d + 2) = make_float2(v.z, v.w);
    }
    FENCE_LGKM();   // 1-wave block: ds writes completed

    const int cp = lane >> 5;
    const int i  = (lane >> 2) & 7;
    const int jh = (lane >> 1) & 1;
    const int eh = lane & 1;

    float2 accp[4] = {{0.f, 0.f}, {0.f, 0.f}, {0.f, 0.f}, {0.f, 0.f}};
    const float* tb = xs + (i + eh) * 36 + jh * 16;
    #pragma unroll
    for (int cin = 0; cin < 2; ++cin) {
        #pragma unroll
        for (int et = 0; et < 4; ++et) {
            const int ro = cin * 1296 + et * 9 * 36;
            float xr[20];
            #pragma unroll
            for (int b = 0; b < 5; ++b)
                *(float4*)(xr + 4 * b) = *(const float4*)(tb + ro + 4 * b);
            // weights from global: pair-interleaved taps for channels (2cp, 2cp+1)
            float4 wt[4];
            const float4* wp4 = (const float4*)(wg + (cin * 8 + eh * 4 + et) * 32 + cp * 16);
            #pragma unroll
            for (int q = 0; q < 4; ++q) wt[q] = wp4[q];
            const float2* wv2 = (const float2*)wt;   // wv2[f] = (w_cl0, w_cl1)
            #pragma unroll
            for (int jj = 0; jj < 4; ++jj) {
                const int o = 4 * jj;
                #pragma unroll
                for (int m = 0; m < 8; ++m) {
                    accp[jj].x += xr[o + m] * wv2[m].x;
                    accp[jj].y += xr[o + m] * wv2[m].y;
                }
            }
        }
    }
    // butterfly over eh-partners (fp add commutes; same tree as R7-R13)
    #pragma unroll
    for (int jj = 0; jj < 4; ++jj) {
        accp[jj].x += __shfl_xor(accp[jj].x, 1);
        accp[jj].y += __shfl_xor(accp[jj].y, 1);
    }
    const float o0 = eh ? accp[0].y : accp[0].x;
    const float o1 = eh ? accp[1].y : accp[1].x;
    const float o2 = eh ? accp[2].y : accp[2].x;
    const float o3 = eh ? accp[3].y : accp[3].x;
    // u1 layout: [n][t][neuron]
    *(float4*)(u1 + (size_t)n * 25600 + t * 256 + (2 * cp + eh) * 64 + i * 8 + jh * 4) =
        make_float4(o0, o1, o2, o3);
}

// ---------------- kf: fused scan1 + conv2(qtr) + scan2 + dense, round-free ----------------
// grid 256 x 256: block = (n, qtr). ls1: 100 x 260 compact slots (104 KB);
// ls2: 100 x 36. Boundary taps rebuilt with selects (values == old pad reads).
__global__ __launch_bounds__(256) void kf(const float* __restrict__ u1,
        const float* __restrict__ wl2g, const float* __restrict__ lw,
        float* __restrict__ out) {
    __shared__ __align__(16) float ls1[100 * 260];  // 104 KB
    __shared__ __align__(16) float ls2[100 * 36];   // 14.4 KB
    const int tid = threadIdx.x;
    const int n = blockIdx.x >> 2, qtr = blockIdx.x & 3;
    const int wave = tid >> 6, l64 = tid & 63;
    const float a = DECAY;

    const float* up = u1 + (size_t)n * 25600 + tid;   // [n][t][neuron]

    const int sub = tid >> 4, l16 = tid & 15;
    const int c2l = l16 >> 3, i2 = (l16 >> 1) & 3, jhp = l16 & 1;
    const int c2g = qtr * 2 + c2l;

    float4 wreg[16];   // [cin*4+e] = folded taps f0..3
    {
        const float* wbase = wl2g + c2g * 68;
        #pragma unroll
        for (int q = 0; q < 16; ++q)
            wreg[q] = *(const float4*)(wbase + (q >> 2) * 16 + (q & 3) * 4);
    }

    float dwA[8], dwB[8];
    {
        const int idx = l64 & 3;
        #pragma unroll
        for (int m = 0; m < 8; ++m) {
            dwA[m] = lw[qtr * 32 + idx * 8 + m];
            dwB[m] = lw[128 + qtr * 32 + idx * 8 + m];
        }
    }

    // --- P1: load all 100 u (coalesced), scan1, publish ---
    float vbuf[100];
    #pragma unroll
    for (int k = 0; k < 100; ++k) vbuf[k] = up[k * 256];
    {
        float psp = 0.f, rr = 0.f;
        #pragma unroll
        for (int k = 0; k < 100; ++k) {
            psp = a * psp + vbuf[k];
            const float vv = psp - rr;
            const float s = (vv >= 1.f) ? 1.f : 0.f;
            rr = a * (rr + s);
            ls1[k * 260 + tid] = s;
        }
    }
    BAR_LGKM();

    // --- P2: conv2, 7 predicated passes x 16 slots ---
    #pragma unroll 1
    for (int pass = 0; pass < 7; ++pass) {
        const int slot = sub + 16 * pass;
        if (slot < 100) {
            const float* sb = ls1 + slot * 260;
            float acc0 = 0.f, acc1 = 0.f;
            #pragma unroll
            for (int cin = 0; cin < 4; ++cin) {
                #pragma unroll
                for (int e = 0; e < 4; ++e) {
                    const int ri = 2 * i2 + e - 1;            // input row, -1..8
                    const int rc = (ri < 0) ? 0 : (ri > 7 ? 7 : ri);
                    const bool rok = (ri >= 0) && (ri <= 7);
                    float rr8[8];
                    const float* rp = sb + cin * 64 + rc * 8;
                    *(float4*)(rr8)     = *(const float4*)(rp);
                    *(float4*)(rr8 + 4) = *(const float4*)(rp + 4);
                    float xr[6];
                    xr[0] = jhp ? rr8[3] : 0.0f;
                    xr[1] = jhp ? rr8[4] : rr8[0];
                    xr[2] = jhp ? rr8[5] : rr8[1];
                    xr[3] = jhp ? rr8[6] : rr8[2];
                    xr[4] = jhp ? rr8[7] : rr8[3];
                    xr[5] = jhp ? 0.0f   : rr8[4];
                    if (!rok) {
                        #pragma unroll
                        for (int m = 0; m < 6; ++m) xr[m] = 0.0f;
                    }
                    const float4 wf = wreg[cin * 4 + e];
                    acc0 += xr[0] * wf.x; acc0 += xr[1] * wf.y;
                    acc0 += xr[2] * wf.z; acc0 += xr[3] * wf.w;
                    acc1 += xr[2] * wf.x; acc1 += xr[3] * wf.y;
                    acc1 += xr[4] * wf.z; acc1 += xr[5] * wf.w;
                }
            }
            *(float2*)(ls2 + slot * 36 + c2l * 16 + i2 * 4 + 2 * jhp) =
                make_float2(acc0, acc1);
        }
    }
    BAR_LGKM();

    // --- tail (wave0): scan2 in-place, fence, dense partials + atomicAdd ---
    if (wave == 0) {
        if (l64 < 32) {
            float psp2 = 0.f, rr2 = 0.f;
            #pragma unroll
            for (int k = 0; k < 100; ++k) {
                const float u = ls2[k * 36 + l64];
                psp2 = a * psp2 + u;
                const float vv = psp2 - rr2;
                const float s = (vv >= 1.f) ? 1.f : 0.f;
                rr2 = a * (rr2 + s);
                ls2[k * 36 + l64] = s;
            }
        }
        FENCE_LGKM();
        const int idx = l64 & 3;
        #pragma unroll 1
        for (int pass = 0; pass < 7; ++pass) {
            const int slot = (l64 >> 2) + 16 * pass;
            if (slot < 100) {
                float a0 = 0.f, a1 = 0.f;
                #pragma unroll
                for (int m = 0; m < 8; ++m) {
                    const float s = ls2[slot * 36 + idx * 8 + m];
                    a0 += s * dwA[m];
                    a1 += s * dwB[m];
                }
                a0 += __shfl_down(a0, 2); a0 += __shfl_down(a0, 1);
                a1 += __shfl_down(a1, 2); a1 += __shfl_down(a1, 1);
                if (idx == 0) {
                    atomicAdd(&out[n * 200 + slot * 2],     a0);
                    atomicAdd(&out[n * 200 + slot * 2 + 1], a1);
                }
            }
        }
    }
}

extern "C" void kernel_launch(void* const* d_in, const int* in_sizes, int n_in,
                              void* d_out, int out_size, void* d_ws, size_t ws_size,
                              hipStream_t stream) {
    const float* x   = (const float*)d_in[0];
    const float* w1  = (const float*)d_in[1];
    const float* w2  = (const float*)d_in[2];
    const float* lw  = (const float*)d_in[3];
    const float* wp1 = (const float*)d_in[4];
    const float* wp2 = (const float*)d_in[5];

    float* u1  = (float*)d_ws;           // 1,638,400 floats ([n][t][neuron])
    float* wl1 = u1 + 1638400;           //       512 floats
    float* wl2 = wl1 + 512;              //       544 floats
    float* out = (float*)d_out;          // (64,100,2) = 12800 floats

    k0_fold<<<1, 128, 0, stream>>>(w1, w2, wp1, wp2, wl1, wl2);
    k1<<<6400, 64, 0, stream>>>(x, wl1, u1, out);
    kf<<<256, 256, 0, stream>>>(u1, wl2, lw, out);
}

// Round 15
// 120.382 us; speedup vs baseline: 1.0356x; 1.0356x over previous
//
#include <hip/hip_runtime.h>

// SLAYER SNN forward, MI355X. Round 15.
// = R13 structure with R14's good parts kept, bad part reverted:
//  - k1 compute loop: R13/R9 version (LDS weights, scalar FMA tree) — the
//    R14 global-weight/pk_fma experiment regressed ~5 us and is reverted.
//  - u1 stays [n][t][neuron] (kf loads one contiguous 100 KB window; k1
//    writes block-contiguous).
//  - out-zeroing stays in k1's first 50 blocks; k0 is 1 block (fold only).
// All summation trees bit-identical to R13 (absmax 0.0 lineage).

#define DECAY 0.9048374180359595f   // exp(-1/10)

#define BAR_LGKM() asm volatile("s_waitcnt lgkmcnt(0)\n\ts_barrier" ::: "memory")
#define FENCE_LGKM() asm volatile("s_waitcnt lgkmcnt(0)" ::: "memory")

// ---------------- k0: fold weights (1 block) ----------------
// wl1[(cin*8 + e)*32 + c*8 + f], e,f in 0..7  (512 floats)
// wl2[c2*68 + cin*16 + e*4 + f]               (544 floats)
__global__ __launch_bounds__(128) void k0_fold(const float* __restrict__ w1,
        const float* __restrict__ w2, const float* __restrict__ wp1,
        const float* __restrict__ wp2, float* __restrict__ wl1,
        float* __restrict__ wl2) {
    const int tid = threadIdx.x;
    const float p1 = wp1[0], p2 = wp2[0];
    for (int idx = tid; idx < 512; idx += 128) {
        const int f = idx & 7, c = (idx >> 3) & 3, e = (idx >> 5) & 7, cin = idx >> 8;
        const int cc = c * 2 + cin;
        int alo = e - 3; if (alo < 0) alo = 0;
        int ahi = e;     if (ahi > 4) ahi = 4;
        int blo = f - 3; if (blo < 0) blo = 0;
        int bhi = f;     if (bhi > 4) bhi = 4;
        float s = 0.f;
        for (int a = alo; a <= ahi; ++a)
            for (int b = blo; b <= bhi; ++b)
                s += w1[cc * 25 + a * 5 + b];
        wl1[(cin * 8 + e) * 32 + c * 8 + f] = s * p1;
    }
    for (int idx = tid; idx < 512; idx += 128) {
        const int c2 = idx & 7, f = (idx >> 3) & 3, e = (idx >> 5) & 3, cin = idx >> 7;
        int alo = e - 1; if (alo < 0) alo = 0;
        int ahi = e;     if (ahi > 2) ahi = 2;
        int blo = f - 1; if (blo < 0) blo = 0;
        int bhi = f;     if (bhi > 2) bhi = 2;
        float s = 0.f;
        for (int aa = alo; aa <= ahi; ++aa)
            for (int bb = blo; bb <= bhi; ++bb)
                s += w2[((c2 * 4 + cin) * 3 + aa) * 3 + bb];
        wl2[c2 * 68 + cin * 16 + e * 4 + f] = s * p2;
    }
}

// ---------------- k1: conv1+pool1, 8x8-tap stride-4 (R13 body) ----------------
// 6400 one-wave blocks; e-split lane pairs; LDS weights; new u1 layout.
__global__ __launch_bounds__(64) void k1(const float* __restrict__ x,
        const float* __restrict__ wg, float* __restrict__ u1,
        float* __restrict__ out) {
    __shared__ __align__(16) float xs[2 * 1296];   // 10.1 KB
    __shared__ __align__(16) float wl[512];        // 2 KB
    const int lane = threadIdx.x;
    const int frame = blockIdx.x;                  // = n*100 + t (x is n-major)
    const int n = frame / 100, t = frame % 100;

    // zero the atomic-target out (12800 floats) across the first 50 blocks
    if (blockIdx.x < 50)
        ((float4*)out)[blockIdx.x * 64 + lane] = make_float4(0.f, 0.f, 0.f, 0.f);

    *(float4*)(wl + 4 * lane)       = *(const float4*)(wg + 4 * lane);
    *(float4*)(wl + 256 + 4 * lane) = *(const float4*)(wg + 256 + 4 * lane);

    #pragma unroll
    for (int m0 = 0; m0 < 128; m0 += 64) {
        const int m = m0 + lane;
        if (m < 72) {
            const int cin = m / 36, rem = m % 36;
            const int rr = rem / 9, q4 = rem % 9;
            const int pr = (rr == 0) ? 0 : (rr == 1) ? 9 : (rr == 2) ? 26 : 35;
            *(float4*)(xs + cin * 1296 + pr * 36 + q4 * 4) = make_float4(0.f, 0.f, 0.f, 0.f);
        }
    }
    #pragma unroll
    for (int m0 = 0; m0 < 192; m0 += 64) {
        const int m = m0 + lane;
        if (m < 144) {
            const int cin = m / 72, rem = m % 72;
            const int side = rem & 1, pr = rem >> 1;
            *(float2*)(xs + cin * 1296 + pr * 36 + side * 34) = make_float2(0.f, 0.f);
        }
    }
    const float4* xg = (const float4*)(x + (size_t)frame * 2048);
    #pragma unroll
    for (int q = 0; q < 8; ++q) {
        const int m = q * 64 + lane;
        const float4 v = xg[m];
        const int li = 4 * m;
        const int cin = li >> 10, row = (li >> 5) & 31, col = li & 31;
        const int r = row + 2;
        const int pr = (r & 3) * 9 + (r >> 2);
        float* d = xs + cin * 1296 + pr * 36 + col + 2;
        *(float2*)(d)     = make_float2(v.x, v.y);
        *(float2*)(d + 2) = make_float2(v.z, v.w);
    }
    FENCE_LGKM();   // 1-wave block: ds writes completed

    const int cp = lane >> 5;
    const int i  = (lane >> 2) & 7;
    const int jh = (lane >> 1) & 1;
    const int eh = lane & 1;

    float acc[2][4] = {{0.f, 0.f, 0.f, 0.f}, {0.f, 0.f, 0.f, 0.f}};
    const float* tb = xs + (i + eh) * 36 + jh * 16;
    #pragma unroll
    for (int cin = 0; cin < 2; ++cin) {
        #pragma unroll
        for (int et = 0; et < 4; ++et) {
            const int ro = cin * 1296 + et * 9 * 36;
            float xr[20];
            #pragma unroll
            for (int b = 0; b < 5; ++b)
                *(float4*)(xr + 4 * b) = *(const float4*)(tb + ro + 4 * b);
            float wv[16];
            const float* wp = wl + (cin * 8 + eh * 4 + et) * 32 + cp * 16;
            #pragma unroll
            for (int q = 0; q < 4; ++q)
                *(float4*)(wv + 4 * q) = *(const float4*)(wp + 4 * q);
            #pragma unroll
            for (int cl = 0; cl < 2; ++cl) {
                #pragma unroll
                for (int jj = 0; jj < 4; ++jj) {
                    const int o = 4 * jj;
                    acc[cl][jj] += xr[o]*wv[cl*8]     + xr[o+1]*wv[cl*8+1]
                                 + xr[o+2]*wv[cl*8+2] + xr[o+3]*wv[cl*8+3]
                                 + xr[o+4]*wv[cl*8+4] + xr[o+5]*wv[cl*8+5]
                                 + xr[o+6]*wv[cl*8+6] + xr[o+7]*wv[cl*8+7];
                }
            }
        }
    }
    #pragma unroll
    for (int cl = 0; cl < 2; ++cl)
        #pragma unroll
        for (int jj = 0; jj < 4; ++jj)
            acc[cl][jj] += __shfl_xor(acc[cl][jj], 1);

    const float o0 = eh ? acc[1][0] : acc[0][0];
    const float o1 = eh ? acc[1][1] : acc[0][1];
    const float o2 = eh ? acc[1][2] : acc[0][2];
    const float o3 = eh ? acc[1][3] : acc[0][3];
    // u1 layout: [n][t][neuron]
    *(float4*)(u1 + (size_t)n * 25600 + t * 256 + (2 * cp + eh) * 64 + i * 8 + jh * 4) =
        make_float4(o0, o1, o2, o3);
}

// ---------------- kf: fused scan1 + conv2(qtr) + scan2 + dense, round-free ----------------
// grid 256 x 256: block = (n, qtr). ls1: 100 x 260 compact slots (104 KB);
// ls2: 100 x 36. Boundary taps rebuilt with selects (values == old pad reads).
__global__ __launch_bounds__(256) void kf(const float* __restrict__ u1,
        const float* __restrict__ wl2g, const float* __restrict__ lw,
        float* __restrict__ out) {
    __shared__ __align__(16) float ls1[100 * 260];  // 104 KB
    __shared__ __align__(16) float ls2[100 * 36];   // 14.4 KB
    const int tid = threadIdx.x;
    const int n = blockIdx.x >> 2, qtr = blockIdx.x & 3;
    const int wave = tid >> 6, l64 = tid & 63;
    const float a = DECAY;

    const float* up = u1 + (size_t)n * 25600 + tid;   // [n][t][neuron]

    const int sub = tid >> 4, l16 = tid & 15;
    const int c2l = l16 >> 3, i2 = (l16 >> 1) & 3, jhp = l16 & 1;
    const int c2g = qtr * 2 + c2l;

    float4 wreg[16];   // [cin*4+e] = folded taps f0..3
    {
        const float* wbase = wl2g + c2g * 68;
        #pragma unroll
        for (int q = 0; q < 16; ++q)
            wreg[q] = *(const float4*)(wbase + (q >> 2) * 16 + (q & 3) * 4);
    }

    float dwA[8], dwB[8];
    {
        const int idx = l64 & 3;
        #pragma unroll
        for (int m = 0; m < 8; ++m) {
            dwA[m] = lw[qtr * 32 + idx * 8 + m];
            dwB[m] = lw[128 + qtr * 32 + idx * 8 + m];
        }
    }

    // --- P1: load all 100 u (coalesced, contiguous window), scan1, publish ---
    float vbuf[100];
    #pragma unroll
    for (int k = 0; k < 100; ++k) vbuf[k] = up[k * 256];
    {
        float psp = 0.f, rr = 0.f;
        #pragma unroll
        for (int k = 0; k < 100; ++k) {
            psp = a * psp + vbuf[k];
            const float vv = psp - rr;
            const float s = (vv >= 1.f) ? 1.f : 0.f;
            rr = a * (rr + s);
            ls1[k * 260 + tid] = s;
        }
    }
    BAR_LGKM();

    // --- P2: conv2, 7 predicated passes x 16 slots ---
    #pragma unroll 1
    for (int pass = 0; pass < 7; ++pass) {
        const int slot = sub + 16 * pass;
        if (slot < 100) {
            const float* sb = ls1 + slot * 260;
            float acc0 = 0.f, acc1 = 0.f;
            #pragma unroll
            for (int cin = 0; cin < 4; ++cin) {
                #pragma unroll
                for (int e = 0; e < 4; ++e) {
                    const int ri = 2 * i2 + e - 1;            // input row, -1..8
                    const int rc = (ri < 0) ? 0 : (ri > 7 ? 7 : ri);
                    const bool rok = (ri >= 0) && (ri <= 7);
                    float rr8[8];
                    const float* rp = sb + cin * 64 + rc * 8;
                    *(float4*)(rr8)     = *(const float4*)(rp);
                    *(float4*)(rr8 + 4) = *(const float4*)(rp + 4);
                    float xr[6];
                    xr[0] = jhp ? rr8[3] : 0.0f;
                    xr[1] = jhp ? rr8[4] : rr8[0];
                    xr[2] = jhp ? rr8[5] : rr8[1];
                    xr[3] = jhp ? rr8[6] : rr8[2];
                    xr[4] = jhp ? rr8[7] : rr8[3];
                    xr[5] = jhp ? 0.0f   : rr8[4];
                    if (!rok) {
                        #pragma unroll
                        for (int m = 0; m < 6; ++m) xr[m] = 0.0f;
                    }
                    const float4 wf = wreg[cin * 4 + e];
                    acc0 += xr[0] * wf.x; acc0 += xr[1] * wf.y;
                    acc0 += xr[2] * wf.z; acc0 += xr[3] * wf.w;
                    acc1 += xr[2] * wf.x; acc1 += xr[3] * wf.y;
                    acc1 += xr[4] * wf.z; acc1 += xr[5] * wf.w;
                }
            }
            *(float2*)(ls2 + slot * 36 + c2l * 16 + i2 * 4 + 2 * jhp) =
                make_float2(acc0, acc1);
        }
    }
    BAR_LGKM();

    // --- tail (wave0): scan2 in-place, fence, dense partials + atomicAdd ---
    if (wave == 0) {
        if (l64 < 32) {
            float psp2 = 0.f, rr2 = 0.f;
            #pragma unroll
            for (int k = 0; k < 100; ++k) {
                const float u = ls2[k * 36 + l64];
                psp2 = a * psp2 + u;
                const float vv = psp2 - rr2;
                const float s = (vv >= 1.f) ? 1.f : 0.f;
                rr2 = a * (rr2 + s);
                ls2[k * 36 + l64] = s;
            }
        }
        FENCE_LGKM();
        const int idx = l64 & 3;
        #pragma unroll 1
        for (int pass = 0; pass < 7; ++pass) {
            const int slot = (l64 >> 2) + 16 * pass;
            if (slot < 100) {
                float a0 = 0.f, a1 = 0.f;
                #pragma unroll
                for (int m = 0; m < 8; ++m) {
                    const float s = ls2[slot * 36 + idx * 8 + m];
                    a0 += s * dwA[m];
                    a1 += s * dwB[m];
                }
                a0 += __shfl_down(a0, 2); a0 += __shfl_down(a0, 1);
                a1 += __shfl_down(a1, 2); a1 += __shfl_down(a1, 1);
                if (idx == 0) {
                    atomicAdd(&out[n * 200 + slot * 2],     a0);
                    atomicAdd(&out[n * 200 + slot * 2 + 1], a1);
                }
            }
        }
    }
}

extern "C" void kernel_launch(void* const* d_in, const int* in_sizes, int n_in,
                              void* d_out, int out_size, void* d_ws, size_t ws_size,
                              hipStream_t stream) {
    const float* x   = (const float*)d_in[0];
    const float* w1  = (const float*)d_in[1];
    const float* w2  = (const float*)d_in[2];
    const float* lw  = (const float*)d_in[3];
    const float* wp1 = (const float*)d_in[4];
    const float* wp2 = (const float*)d_in[5];

    float* u1  = (float*)d_ws;           // 1,638,400 floats ([n][t][neuron])
    float* wl1 = u1 + 1638400;           //       512 floats
    float* wl2 = wl1 + 512;              //       544 floats
    float* out = (float*)d_out;          // (64,100,2) = 12800 floats

    k0_fold<<<1, 128, 0, stream>>>(w1, w2, wp1, wp2, wl1, wl2);
    k1<<<6400, 64, 0, stream>>>(x, wl1, u1, out);
    kf<<<256, 256, 0, stream>>>(u1, wl2, lw, out);
}